// Round 5
// baseline (508.858 us; speedup 1.0000x reference)
//
#include <hip/hip_runtime.h>
#include <hip/hip_bf16.h>
#include <cstddef>

// Problem constants
// B=4, H=W=64, DIM=768, HEADS=12, HD=64, STRIDE=2, N=4097, pooled tokens=1025
#define NTOK 4097
#define NPOOL 1025
#define DIMC 768

typedef short  s16x8 __attribute__((ext_vector_type(8)));
typedef float  f32x4 __attribute__((ext_vector_type(4)));
typedef unsigned short u16x8 __attribute__((ext_vector_type(8)));

static __device__ inline unsigned short f2bf(float x) {
    __hip_bfloat16 h = __float2bfloat16(x);
    return *reinterpret_cast<unsigned short*>(&h);
}
static __device__ inline float bf2f(unsigned short u) {
    __hip_bfloat16 h;
    *reinterpret_cast<unsigned short*>(&h) = u;
    return __bfloat162float(h);
}

#define GLDS(gp, lp) __builtin_amdgcn_global_load_lds(                        \
    (const __attribute__((address_space(1))) void*)(gp),                      \
    (__attribute__((address_space(3))) void*)(lp), 16, 0, 0)

// ---------------------------------------------------------------------------
// Pad + convert f32 [rows_valid][768] -> bf16 [rows_pad][768] (pad rows zero).
// ---------------------------------------------------------------------------
__global__ __launch_bounds__(256) void cvt_pad(const float* __restrict__ in,
                                               unsigned short* __restrict__ out,
                                               int rows_valid, int groups) {
    const int g = blockIdx.x * 256 + threadIdx.x;
    if (g >= groups) return;
    const int row = g / 96, off = (g - row * 96) * 8;
    u16x8 o;
    if (row < rows_valid) {
        const float4 v0 = *(const float4*)(in + (size_t)row * DIMC + off);
        const float4 v1 = *(const float4*)(in + (size_t)row * DIMC + off + 4);
        o[0] = f2bf(v0.x); o[1] = f2bf(v0.y); o[2] = f2bf(v0.z); o[3] = f2bf(v0.w);
        o[4] = f2bf(v1.x); o[5] = f2bf(v1.y); o[6] = f2bf(v1.z); o[7] = f2bf(v1.w);
    } else {
        o = (u16x8){0, 0, 0, 0, 0, 0, 0, 0};
    }
    *(u16x8*)(out + (size_t)g * 8) = o;
}

// ---------------------------------------------------------------------------
// Transpose + convert: in f32 [R][C] -> out bf16 [C][R]. R,C % 32 == 0.
// ---------------------------------------------------------------------------
__global__ __launch_bounds__(256) void transpose_cvt(const float* __restrict__ in,
                                                     unsigned short* __restrict__ out,
                                                     int R, int C) {
    __shared__ float t[32][33];
    const int tx = threadIdx.x & 31, ty = threadIdx.x >> 5;   // ty 0..7
    const int r0 = blockIdx.y * 32, c0 = blockIdx.x * 32;
#pragma unroll
    for (int i = 0; i < 32; i += 8)
        t[ty + i][tx] = in[(size_t)(r0 + ty + i) * C + c0 + tx];
    __syncthreads();
#pragma unroll
    for (int i = 0; i < 32; i += 8)
        out[(size_t)(c0 + ty + i) * R + r0 + tx] = f2bf(t[tx][ty + i]);
}

// ---------------------------------------------------------------------------
// bf16 MFMA GEMM: C = A[Mpad,K](bf16) @ Bt[N,K](bf16)^T.
// 128x128 tile, BK=32, 4 waves (2x2), 4x4 frags of 16x16x32.
// Swapped-operand mfma -> each lane owns 4 consecutive N-cols at one row
// (coalesced epilogue). 2-phase prefetch (double-buffered LDS). XCD swizzle.
// out_bf: 1 -> store bf16 (u16), 0 -> store f32 (+bias).
// ---------------------------------------------------------------------------
static __device__ inline void stage_tiles(const unsigned short* aG,
                                          const unsigned short* bG,
                                          short* aL, short* bL, int w, int K) {
    short* a = aL + w * 1024;
    short* b = bL + w * 1024;
    GLDS(aG, a); GLDS(aG + 16 * (size_t)K, a + 512);
    GLDS(bG, b); GLDS(bG + 16 * (size_t)K, b + 512);
}

static __device__ inline void compute_tile(const short* As_, const short* Bs_,
                                           int ar, int br, int ko,
                                           f32x4 acc[4][4]) {
    s16x8 af[4], bf[4];
#pragma unroll
    for (int m = 0; m < 4; ++m)
        af[m] = *(const s16x8*)&As_[(ar + m * 16) * 32 + ko];
#pragma unroll
    for (int n = 0; n < 4; ++n)
        bf[n] = *(const s16x8*)&Bs_[(br + n * 16) * 32 + ko];
#pragma unroll
    for (int m = 0; m < 4; ++m)
#pragma unroll
        for (int n = 0; n < 4; ++n)
            acc[m][n] = __builtin_amdgcn_mfma_f32_16x16x32_bf16(bf[n], af[m], acc[m][n], 0, 0, 0);
}

__global__ __launch_bounds__(256) void gemm_bf16(const unsigned short* __restrict__ A,
                                                 const unsigned short* __restrict__ Bt,
                                                 const float* __restrict__ bias,
                                                 void* __restrict__ Cv,
                                                 int M, int N, int K, int out_bf) {
    __shared__ __align__(16) short As0[4096], Bs0[4096], As1[4096], Bs1[4096];
    const int tid = threadIdx.x;
    const int w = tid >> 6, lane = tid & 63;

    // bijective XCD-aware remap of the linear block id (m204 formula)
    const unsigned nwg = gridDim.x * gridDim.y;
    const unsigned lin = blockIdx.y * gridDim.x + blockIdx.x;
    const unsigned qq = nwg >> 3, rr = nwg & 7;
    const unsigned xcd = lin & 7, off = lin >> 3;
    const unsigned lin2 = (xcd < rr ? xcd * (qq + 1) : rr * (qq + 1) + (xcd - rr) * qq) + off;
    const int bx = lin2 % gridDim.x, by = lin2 / gridDim.x;
    const int bm = by * 128, bn = bx * 128;

    const int sr = lane >> 2, sc8 = (lane & 3) * 8;
    const unsigned short* aG = A + (size_t)(bm + w * 32 + sr) * K + sc8;
    const unsigned short* bG = Bt + (size_t)(bn + w * 32 + sr) * K + sc8;

    f32x4 acc[4][4];
#pragma unroll
    for (int m = 0; m < 4; ++m)
#pragma unroll
        for (int n = 0; n < 4; ++n) acc[m][n] = (f32x4){0.f, 0.f, 0.f, 0.f};

    const int wr = w >> 1, wc = w & 1;
    const int ar = wr * 64 + (lane & 15);
    const int br = wc * 64 + (lane & 15);
    const int ko = (lane >> 4) * 8;

    stage_tiles(aG, bG, As0, Bs0, w, K);
    aG += 32; bG += 32;
    const int T = K >> 5;
    for (int t = 0; t < T; ++t) {
        __syncthreads();
        const bool last = (t + 1 == T);
        if ((t & 1) == 0) {
            if (!last) { stage_tiles(aG, bG, As1, Bs1, w, K); aG += 32; bG += 32; }
            compute_tile(As0, Bs0, ar, br, ko, acc);
        } else {
            if (!last) { stage_tiles(aG, bG, As0, Bs0, w, K); aG += 32; bG += 32; }
            compute_tile(As1, Bs1, ar, br, ko, acc);
        }
    }

    // Epilogue: row = M-row (lane&15 within frag), 4 consecutive cols per acc.
    const int mrow0 = bm + wr * 64 + (lane & 15);
    const int cb0 = bn + wc * 64 + (lane >> 4) * 4;
    if (out_bf) {
        unsigned short* C = (unsigned short*)Cv;
#pragma unroll
        for (int m = 0; m < 4; ++m) {
            const int row = mrow0 + m * 16;
            if (row >= M) continue;
#pragma unroll
            for (int n = 0; n < 4; ++n) {
                const int col = cb0 + n * 16;
                const f32x4 v = acc[m][n];
                unsigned int lo = f2bf(v[0]) | ((unsigned int)f2bf(v[1]) << 16);
                unsigned int hi = f2bf(v[2]) | ((unsigned int)f2bf(v[3]) << 16);
                *(uint2*)&C[(size_t)row * N + col] = make_uint2(lo, hi);
            }
        }
    } else {
        float* C = (float*)Cv;
        f32x4 bv[4];
#pragma unroll
        for (int n = 0; n < 4; ++n)
            bv[n] = bias ? *(const f32x4*)(bias + cb0 + n * 16)
                         : (f32x4){0.f, 0.f, 0.f, 0.f};
#pragma unroll
        for (int m = 0; m < 4; ++m) {
            const int row = mrow0 + m * 16;
            if (row >= M) continue;
#pragma unroll
            for (int n = 0; n < 4; ++n) {
                const int col = cb0 + n * 16;
                f32x4 v = acc[m][n] + bv[n];
                *(f32x4*)&C[(size_t)row * N + col] = v;
            }
        }
    }
}

// ---------------------------------------------------------------------------
// Pool: depthwise 3x3 stride-2 SAME conv on the head-shuffled grid view (bf16
// qkv input), then per-(head,token) LayerNorm over 64 channels (wave reduce).
// which==0 -> qp f32 + qp_bf ; which==1 -> kp_bf ; which==2 -> vt_bf (transposed)
// ---------------------------------------------------------------------------
__global__ __launch_bounds__(256) void pool_ln_kernel(
    const unsigned short* __restrict__ qkv,
    const float* __restrict__ dwq, const float* __restrict__ dwk, const float* __restrict__ dwv,
    const float* __restrict__ gq, const float* __restrict__ bq,
    const float* __restrict__ gk, const float* __restrict__ bk,
    const float* __restrict__ gv, const float* __restrict__ bv,
    float* __restrict__ qp, unsigned short* __restrict__ qbf,
    unsigned short* __restrict__ kbf, unsigned short* __restrict__ vtbf) {
    const int pos = blockIdx.x;          // 0..1023 spatial, 1024 = cls
    const int which = blockIdx.y;        // 0=q,1=k,2=v
    const int bi = blockIdx.z;
    const float* w   = which == 0 ? dwq : which == 1 ? dwk : dwv;
    const float* gam = which == 0 ? gq  : which == 1 ? gk  : gv;
    const float* bet = which == 0 ? bq  : which == 1 ? bk  : bv;
    const int wave = threadIdx.x >> 6, lane = threadIdx.x & 63;
    const size_t base = (size_t)bi * NTOK * 2304 + (size_t)which * DIMC;

    for (int db = wave; db < 12; db += 4) {
        float val;
        int h, tok;
        if (pos == 1024) {
            h = db; tok = 0;
            val = bf2f(qkv[base + (size_t)db * 64 + lane]);
        } else {
            const int oh = pos >> 5, ow = pos & 31;
            const int d = db * 64 + lane;
            float acc = 0.f;
#pragma unroll
            for (int kh = 0; kh < 3; ++kh) {
                const int ih = oh * 2 + kh;             // pad_lo = 0
#pragma unroll
                for (int kw = 0; kw < 3; ++kw) {
                    const int iw = ow * 2 + kw;
                    if (ih < 64 && iw < 64) {
                        const int m = (ih * 64 + iw) * DIMC + d;   // grid-flat offset
                        const int hin = m >> 18;
                        const int l   = (m >> 6) & 4095;
                        const int ci  = m & 63;
                        acc += bf2f(qkv[base + (size_t)(1 + l) * 2304 + hin * 64 + ci])
                             * w[(kh * 3 + kw) * DIMC + d];
                    }
                }
            }
            val = acc;
            const int idx = pos * 12 + db;
            h = idx >> 10;
            tok = 1 + (idx & 1023);
        }
        // LayerNorm over 64 lanes
        float s = val;
#pragma unroll
        for (int o = 32; o > 0; o >>= 1) s += __shfl_xor(s, o);
        const float mu = s * (1.f / 64.f);
        const float dv = val - mu;
        float s2 = dv * dv;
#pragma unroll
        for (int o = 32; o > 0; o >>= 1) s2 += __shfl_xor(s2, o);
        const float inv = rsqrtf(s2 * (1.f / 64.f) + 1e-3f);
        const float res = dv * inv * gam[lane] + bet[lane];
        const size_t bh = (size_t)(bi * 12 + h);
        if (which == 0) {
            qp[(bh * NPOOL + tok) * 64 + lane] = res;
            qbf[(bh * 1040 + tok) * 64 + lane] = f2bf(res);
        } else if (which == 1) {
            kbf[(bh * 1056 + tok) * 64 + lane] = f2bf(res);
        } else {
            vtbf[(bh * 64 + lane) * 1056 + tok] = f2bf(res);
        }
    }
}

// ---------------------------------------------------------------------------
// rel tables: relH[b,y,pos,kh] = sum_c qpool[b,y,1+pos,c]*rel_pos_h[qh-kh+31][c]
// ---------------------------------------------------------------------------
__global__ __launch_bounds__(256) void rel_kernel(const float* __restrict__ qp,
                                                  const float* __restrict__ rph,
                                                  const float* __restrict__ rpw,
                                                  float* __restrict__ relH,
                                                  float* __restrict__ relW) {
    __shared__ float qs[4][64];
    const int wave = threadIdx.x >> 6, lane = threadIdx.x & 63;
    const int r = blockIdx.x * 4 + wave;
    const int bh = r >> 10, pos = r & 1023;
    const int qh = pos >> 5, qw = pos & 31;
    qs[wave][lane] = qp[((size_t)bh * NPOOL + 1 + pos) * 64 + lane];
    __syncthreads();
    const int kj = lane & 31;
    const float* tab = (lane < 32) ? (rph + (qh - kj + 31) * 64)
                                   : (rpw + (qw - kj + 31) * 64);
    float acc = 0.f;
#pragma unroll
    for (int c = 0; c < 64; ++c) acc += qs[wave][c] * tab[c];
    if (lane < 32) relH[(size_t)r * 32 + kj] = acc;
    else           relW[(size_t)r * 32 + kj] = acc;
}

// ---------------------------------------------------------------------------
// MFMA attention, 8 waves. Block = (bh, 16 q-rows). Swapped-operand mfma:
// pass1 lane owns 4 consecutive kcols at one qrow (f32x4 LDS store);
// pass3 lane owns 4 consecutive d at one qrow (dwordx4 global store).
// ---------------------------------------------------------------------------
#define LSTR 1060
__global__ __launch_bounds__(512) void attn_mfma(
    const unsigned short* __restrict__ qbf, const unsigned short* __restrict__ kbf,
    const unsigned short* __restrict__ vtbf, const float* __restrict__ qpf,
    const float* __restrict__ relH, const float* __restrict__ relW,
    float* __restrict__ outp) {
    __shared__ float logits_s[16 * LSTR];
    __shared__ float relh_s[16][32];
    __shared__ float relw_s[16][32];
    __shared__ __align__(16) float partial_s[4][16][20];
    __shared__ float srow_s[16];
    const int bh = blockIdx.y, bi = bh / 12, hh = bh % 12;
    const int q0 = blockIdx.x * 16;
    const int tid = threadIdx.x, w = tid >> 6, lane = tid & 63;

    // rel rows for this q-tile into LDS (512 threads -> one element each)
    {
        const int qi = tid >> 5, j = tid & 31;
        const int qg = q0 + qi;
        float rh = 0.f, rw = 0.f;
        if (qg >= 1 && qg < NPOOL) {
            const size_t rb = ((size_t)bh * 1024 + (qg - 1)) * 32;
            rh = relH[rb + j]; rw = relW[rb + j];
        }
        relh_s[qi][j] = rh; relw_s[qi][j] = rw;
    }

    const int frow = lane & 15, fcol = (lane >> 4) * 8;
    const unsigned short* qrow_p = qbf + ((size_t)bh * 1040 + q0 + frow) * 64 + fcol;
    s16x8 aq0 = *(const s16x8*)qrow_p;
    s16x8 aq1 = *(const s16x8*)(qrow_p + 32);
    __syncthreads();

    // ---- pass 1: logits (swapped: lane -> qrow=lane&15, 4 consecutive kcols) ----
    const int qrow1 = frow, qg1 = q0 + qrow1;
    for (int t = w; t < 66; t += 8) {
        const int k0 = t * 16;
        const unsigned short* kb = kbf + ((size_t)bh * 1056 + k0 + frow) * 64 + fcol;
        s16x8 b0 = *(const s16x8*)kb;
        s16x8 b1 = *(const s16x8*)(kb + 32);
        f32x4 s = (f32x4){0.f, 0.f, 0.f, 0.f};
        s = __builtin_amdgcn_mfma_f32_16x16x32_bf16(b0, aq0, s, 0, 0, 0);
        s = __builtin_amdgcn_mfma_f32_16x16x32_bf16(b1, aq1, s, 0, 0, 0);
        const int kbase = k0 + (lane >> 4) * 4;
        f32x4 outv;
#pragma unroll
        for (int r = 0; r < 4; ++r) {
            const int kcol = kbase + r;
            float v;
            if (kcol >= NPOOL) {
                v = -3.0e38f;
            } else {
                v = s[r] * 0.125f;
                if (kcol >= 1 && qg1 >= 1)
                    v += relh_s[qrow1][(kcol - 1) >> 5] + relw_s[qrow1][(kcol - 1) & 31];
            }
            outv[r] = v;
        }
        *(f32x4*)&logits_s[qrow1 * LSTR + kbase] = outv;
    }
    __syncthreads();

    // ---- pass 2: softmax (2 rows/wave) ----
    for (int qi = w; qi < 16; qi += 8) {
        float m = -3.0e38f;
        for (int k = lane; k < 1056; k += 64) m = fmaxf(m, logits_s[qi * LSTR + k]);
#pragma unroll
        for (int o = 32; o > 0; o >>= 1) m = fmaxf(m, __shfl_xor(m, o));
        float sum = 0.f;
        for (int k = lane; k < 1056; k += 64) {
            const float p = __expf(logits_s[qi * LSTR + k] - m);
            logits_s[qi * LSTR + k] = p;
            sum += p;
        }
#pragma unroll
        for (int o = 32; o > 0; o >>= 1) sum += __shfl_xor(sum, o);
        if (lane == 0) srow_s[qi] = sum;
    }
    __syncthreads();

    // ---- pass 3: PV, split (d-frag f) x (k-half h) ----
    const int f = w & 3, h = w >> 2;
    const int cstart = h ? 17 : 0, cend = h ? 33 : 17;
    const unsigned short* vrow = vtbf + ((size_t)bh * 64 + f * 16 + frow) * 1056 + fcol;
    f32x4 acc = (f32x4){0.f, 0.f, 0.f, 0.f};
    for (int c = cstart; c < cend; ++c) {
        const float* pp = &logits_s[frow * LSTR + c * 32 + fcol];
        f32x4 p0 = *(const f32x4*)pp;
        f32x4 p1 = *(const f32x4*)(pp + 4);
        s16x8 pa;
        pa[0] = (short)f2bf(p0[0]); pa[1] = (short)f2bf(p0[1]);
        pa[2] = (short)f2bf(p0[2]); pa[3] = (short)f2bf(p0[3]);
        pa[4] = (short)f2bf(p1[0]); pa[5] = (short)f2bf(p1[1]);
        pa[6] = (short)f2bf(p1[2]); pa[7] = (short)f2bf(p1[3]);
        s16x8 vb = *(const s16x8*)(vrow + c * 32);
        acc = __builtin_amdgcn_mfma_f32_16x16x32_bf16(vb, pa, acc, 0, 0, 0);
    }
    // swapped: lane owns qrow = lane&15, d = f*16 + (lane>>4)*4 + {0..3}
    const int qrow = frow, qg = q0 + qrow;
    const int s0 = (lane >> 4) * 4;
    if (h == 1) {
        *(f32x4*)&partial_s[f][qrow][s0] = acc;
    }
    __syncthreads();
    if (h == 0 && qg < NPOOL) {
        const f32x4 other = *(const f32x4*)&partial_s[f][qrow][s0];
        const int d0 = f * 16 + s0;
        const float inv = 1.f / srow_s[qrow];
        const f32x4 res = *(const f32x4*)&qpf[((size_t)bh * NPOOL + qg) * 64 + d0];
        f32x4 o;
#pragma unroll
        for (int r = 0; r < 4; ++r) o[r] = (acc[r] + other[r]) * inv + res[r];
        *(f32x4*)&outp[((size_t)bi * NPOOL + qg) * DIMC + hh * 64 + d0] = o;
    }
}

// ---------------------------------------------------------------------------
extern "C" void kernel_launch(void* const* d_in, const int* in_sizes, int n_in,
                              void* d_out, int out_size, void* d_ws, size_t ws_size,
                              hipStream_t stream) {
    const float* x     = (const float*)d_in[0];
    const float* wqkv  = (const float*)d_in[1];
    const float* dwq   = (const float*)d_in[2];
    const float* dwk   = (const float*)d_in[3];
    const float* dwv   = (const float*)d_in[4];
    const float* gq    = (const float*)d_in[5];
    const float* bq    = (const float*)d_in[6];
    const float* gk    = (const float*)d_in[7];
    const float* bk    = (const float*)d_in[8];
    const float* gv    = (const float*)d_in[9];
    const float* bv    = (const float*)d_in[10];
    const float* rph   = (const float*)d_in[11];
    const float* rpw   = (const float*)d_in[12];
    const float* wproj = (const float*)d_in[13];
    const float* bproj = (const float*)d_in[14];
    float* out = (float*)d_out;
    float* ws_f = (float*)d_ws;

    // Workspace layout (f32 units):
    //   [0, A)  qkv_bf u16 (16388x2304); recycled after pool for
    //           relH/relW/outpre/outpre_bf/wproj_bf
    //   A = 37,757,952:
    //     qp    f32  A+0         (3,148,800)
    //     qp_bf u16  A+3,148,800 (1,597,440 f32-eq)  48 x 1040 x 64
    //     kp_bf u16  A+4,746,240 (1,622,016 f32-eq)  48 x 1056 x 64
    //     vt_bf u16  A+6,368,256 (1,622,016 f32-eq)  48 x 64 x 1056
    //     wqkv_bf u16 A+7,990,272 (884,736 f32-eq)
    //   x_bf u16 @ A (6,340,608 f32-eq) - dead after gemm1; pool overwrites.
    const size_t A = 37757952;
    unsigned short* qkv_bf = (unsigned short*)ws_f;
    float* qp = ws_f + A;
    unsigned short* qp_bf = (unsigned short*)(ws_f + A + 3148800);
    unsigned short* kp_bf = (unsigned short*)(ws_f + A + 4746240);
    unsigned short* vt_bf = (unsigned short*)(ws_f + A + 6368256);
    unsigned short* wqkv_bf = (unsigned short*)(ws_f + A + 7990272);
    unsigned short* x_bf = (unsigned short*)qp;
    float* relH   = ws_f;
    float* relW   = ws_f + 1572864;
    float* outpre = ws_f + 3145728;
    unsigned short* outpre_bf = (unsigned short*)(ws_f + 6294528);
    unsigned short* wproj_bf  = (unsigned short*)(ws_f + 7916544);

    // 0) zero V^T pad columns (whole buffer, 6.5 MB)
    hipMemsetAsync(vt_bf, 0, (size_t)48 * 64 * 1056 * 2, stream);
    // 1) convert + pad A, transpose + convert B for the qkv GEMM
    cvt_pad<<<(16512 * 96 + 255) / 256, 256, 0, stream>>>(x, x_bf, 16388, 16512 * 96);
    transpose_cvt<<<dim3(2304 / 32, 768 / 32), 256, 0, stream>>>(wqkv, wqkv_bf, 768, 2304);
    // 2) QKV GEMM (bf16 MFMA): (16388 x 768) @ (768 x 2304) -> bf16
    gemm_bf16<<<dim3(18, 129), 256, 0, stream>>>(x_bf, wqkv_bf, nullptr, qkv_bf, 16388, 2304, 768, 1);
    // 3) conv-pool + LayerNorm -> qp f32, qp/kp bf16, V^T bf16
    pool_ln_kernel<<<dim3(1025, 3, 4), 256, 0, stream>>>(qkv_bf, dwq, dwk, dwv,
                                                         gq, bq, gk, bk, gv, bv,
                                                         qp, qp_bf, kp_bf, vt_bf);
    // 4) rel_h / rel_w tables
    rel_kernel<<<dim3(12288), 256, 0, stream>>>(qp, rph, rpw, relH, relW);
    // 5) MFMA attention (8 waves) + residual -> outpre (b, tok, 768)
    attn_mfma<<<dim3(65, 48), 512, 0, stream>>>(qp_bf, kp_bf, vt_bf, qp, relH, relW, outpre);
    // 6) proj GEMM (bf16 MFMA): (4100 x 768) @ (768 x 768) + bias -> f32 out
    cvt_pad<<<(4224 * 96 + 255) / 256, 256, 0, stream>>>(outpre, outpre_bf, 4100, 4224 * 96);
    transpose_cvt<<<dim3(768 / 32, 768 / 32), 256, 0, stream>>>(wproj, wproj_bf, 768, 768);
    gemm_bf16<<<dim3(6, 33), 256, 0, stream>>>(outpre_bf, wproj_bf, bproj, out, 4100, 768, 768, 0);
}